// Round 5
// baseline (1170.538 us; speedup 1.0000x reference)
//
#include <hip/hip_runtime.h>

#define DI __device__ __forceinline__

typedef __attribute__((ext_vector_type(8))) short v8s;
typedef __attribute__((ext_vector_type(4))) short v4s;
typedef __attribute__((ext_vector_type(4))) float v4f;
typedef unsigned long long u64;

constexpr int BB = 16, NN = 4096, CH = 64, SS = 1024, KK = 32, DD = 128;
constexpr int LDW = 136;                 // LDS row stride in shorts (pad: 16B-aligned rows, <=2-way banks)
constexpr int GPC = 2;                   // groups per chunk in gemm passes
constexpr int GGRID = 512;

// ---- ws layout (bytes) ----
constexpr size_t OFF_FPSIDX = 0;         // int[16384]
constexpr size_t OFF_KNN    = 65536;     // int[524288]
constexpr size_t OFF_MEAN   = 2162688;   // float[1048576]
constexpr size_t OFF_VARB   = 6356992;   // float[1024]
constexpr size_t OFF_BINS1  = 6361088;   // float[16384]  [64][128][2]
constexpr size_t OFF_BINS2  = 6426624;   // float[16384]
constexpr size_t OFF_RSTD   = 6492160;   // float[16]
constexpr size_t OFF_COEF1  = 6492224;   // float[256]
constexpr size_t OFF_COEF2  = 6493248;   // float[256]
constexpr size_t OFF_W1BF   = 6494272;   // short[16384]
constexpr size_t OFF_W2BF   = 6527040;   // short[16384]
constexpr size_t OFF_XYZT   = 6559808;   // float[196608]  [B][3][N]
constexpr size_t MEMSET_OFF = OFF_VARB;
constexpr size_t MEMSET_LEN = 4096 + 65536 + 65536;

DI short f2bf(float f) {
  unsigned u = __float_as_uint(f);
  u = (u + 0x7fffu + ((u >> 16) & 1u)) >> 16;
  return (short)u;
}
DI float bf2f(short s) { return __uint_as_float(((unsigned)(unsigned short)s) << 16); }

// packed 2x f32 -> 2x bf16 (RNE); HW packed cvt if available
DI unsigned pkbf(float a, float b) {
#if __has_builtin(__builtin_amdgcn_cvt_pk_bf16_f32)
  typedef __attribute__((ext_vector_type(2))) __bf16 bf2_t;
  bf2_t r = __builtin_amdgcn_cvt_pk_bf16_f32(a, b);
  return *(unsigned*)&r;
#else
  return (unsigned)(unsigned short)f2bf(a) | ((unsigned)(unsigned short)f2bf(b) << 16);
#endif
}

// ---------------- prep: xyz transpose + weight cvt (merged launch) ----------------
__global__ void prep_kernel(const float* __restrict__ xyz, float* __restrict__ xyzT,
                            const float* __restrict__ w1, const float* __restrict__ w2,
                            short* __restrict__ w1b, short* __restrict__ w2b) {
  int bid = blockIdx.x;
  if (bid < 256) {
    int i = bid * 256 + threadIdx.x;  // < B*N
    int b = i >> 12, n = i & 4095;
    const float* s = xyz + (size_t)i * 3;
    float* d = xyzT + (size_t)b * 3 * NN + n;
    d[0] = s[0]; d[NN] = s[1]; d[2 * NN] = s[2];
  } else {
    int i = (bid - 256) * 256 + threadIdx.x;  // < 16384
    w1b[i] = f2bf(w1[i]);
    w2b[i] = f2bf(w2[i]);
  }
}

// DPP row rotate (within 16-lane row) for f32 reductions -- no LDS traffic.
template <int N>
DI float dpp_ror_f(float v) {
  return __int_as_float(__builtin_amdgcn_update_dpp(0, __float_as_int(v), 0x120 + N, 0xf, 0xf, true));
}
DI float sum16(float v) {
  v += dpp_ror_f<1>(v);
  v += dpp_ror_f<2>(v);
  v += dpp_ror_f<4>(v);
  v += dpp_ror_f<8>(v);
  return v;
}
DI float max16(float v) {
  v = fmaxf(v, dpp_ror_f<1>(v));
  v = fmaxf(v, dpp_ror_f<2>(v));
  v = fmaxf(v, dpp_ror_f<4>(v));
  v = fmaxf(v, dpp_ror_f<8>(v));
  return v;
}

// ---- u64-key max DPP machinery for FPS (full-rate; single combined chain) ----
template <int CTRL>
DI u64 dpp_maxu64(u64 x) {
  // old=0 is the identity for unsigned max (non-receiving lanes keep x via max)
  int lo = __builtin_amdgcn_update_dpp(0, (int)(unsigned)x, CTRL, 0xf, 0xf, true);
  int hi = __builtin_amdgcn_update_dpp(0, (int)(unsigned)(x >> 32), CTRL, 0xf, 0xf, true);
  u64 o = ((u64)(unsigned)hi << 32) | (unsigned)lo;
  return x > o ? x : o;
}
// full-wave u64 max; result valid in lane 63 (canonical 6-stage pattern, verified in v11)
DI u64 wave_maxu64(u64 x) {
  x = dpp_maxu64<0xB1>(x);   // quad_perm xor1
  x = dpp_maxu64<0x4E>(x);   // quad_perm xor2
  x = dpp_maxu64<0x141>(x);  // ROW_HALF_MIRROR
  x = dpp_maxu64<0x140>(x);  // ROW_MIRROR   -> all lanes hold row max
  x = dpp_maxu64<0x142>(x);  // ROW_BCAST15  -> row r+1 absorbs row r
  x = dpp_maxu64<0x143>(x);  // ROW_BCAST31  -> rows 2,3 absorb max(r0,r1)
  return x;
}

// ---------------- FPS v12: f32-exact inner + single-phase u64-key reduce ----------------
// v11 post-mortem: round is STALL-bound (VALUBusy fell 3.97->2.94 yet time rose);
// the two-phase tail (value DPP -> readlane M -> 16-deep serial select -> second
// DPP chain) lengthened the serial critical path. v12 keeps the bit-exact f32
// inner (proven v10/v11) and collapses the tail to ONE chain at full rate:
//   - per-thread (bits,k) pair tree, ">=" on the lower-k side => min-index ties,
//     k in 0..15 stays inline-constant;
//   - ONE u64 key (bits<<12)|tag, tag=4095-gi (distinct; larger tag = smaller
//     index) -> single 6-stage DPP u64-max wave reduce -> lane63 -> LDS;
//   - barrier; uniform 3-compare u64 scan -> fi.
// Ordering identical to v10/v11's (monotone value map + min-gi ties) =>
// selections bit-identical to two passing versions.
// Decision rule: if fps >= 567us (v7 level), revert fps to v7 and move on.
__global__ __launch_bounds__(256, 1) void fps_kernel(const float* __restrict__ xyzT,
                                                     int* __restrict__ fps_idx,
                                                     float* __restrict__ out_xyz) {
  int b = blockIdx.x, tid = threadIdx.x;
  int wave = tid >> 6, lane = tid & 63;
  const float* bx = xyzT + (size_t)b * 3 * NN;
  const float* by = bx + NN;
  const float* bz = bx + 2 * NN;
  __shared__ float4 s_xyzw[NN];              // 64 KB coords broadcast
  __shared__ int s_fidx[SS];                 // 4 KB selected indices
  __shared__ alignas(32) u64 s_pd[2][4];     // per-wave u64 keys, dbuf by parity

  float px[16], py[16], pz[16], m32[16];
  int tagbase = 4095 - tid;  // tag for point k: tagbase - k*256 == 4095 - gi
#pragma unroll
  for (int k = 0; k < 16; ++k) {
    int gi = k * 256 + tid;
    float x = bx[gi], y = by[gi], z = bz[gi];
    float xs = x, ys = y, zs = z;
    asm volatile("" : "+v"(xs));
    asm volatile("" : "+v"(ys));
    asm volatile("" : "+v"(zs));
    s_xyzw[gi] = make_float4(xs, ys, zs, 0.f);  // bit-identical, opaque to value-tracking
    px[k] = x; py[k] = y; pz[k] = z;
    m32[k] = 1e10f;
  }
  // Keep the f32 coords register-resident (48 VGPRs; budget 512 at 1 wave/SIMD).
#pragma unroll
  for (int k = 0; k < 16; ++k) {
    asm volatile("" : "+v"(px[k]));
    asm volatile("" : "+v"(py[k]));
    asm volatile("" : "+v"(pz[k]));
  }
  if (tid == 0) s_fidx[0] = 0;
  __syncthreads();
  float4 c0 = s_xyzw[0];
  float cx = c0.x, cy = c0.y, cz = c0.z;

  for (int j = 1; j < SS; ++j) {
    // ---- inner: EXACT reference association ((dx^2 + dy^2) + dz^2), no fma ----
#pragma unroll
    for (int k = 0; k < 16; ++k) {
      float dx = px[k] - cx, dy = py[k] - cy, dz = pz[k] - cz;
      float d = __fadd_rn(__fadd_rn(__fmul_rn(dx, dx), __fmul_rn(dy, dy)), __fmul_rn(dz, dz));
      m32[k] = fminf(m32[k], d);
    }
    // ---- per-thread (bits, k) tree: >= on lower-k side => smallest k on ties ----
    unsigned nb[8], nk[8];
#pragma unroll
    for (int k = 0; k < 8; ++k) {
      unsigned ba = __float_as_uint(m32[2 * k]), bbv = __float_as_uint(m32[2 * k + 1]);
      bool c = ba >= bbv;
      nb[k] = c ? ba : bbv;
      nk[k] = c ? (unsigned)(2 * k) : (unsigned)(2 * k + 1);
    }
#pragma unroll
    for (int k = 0; k < 4; ++k) {
      bool c = nb[2 * k] >= nb[2 * k + 1];
      nb[k] = c ? nb[2 * k] : nb[2 * k + 1];
      nk[k] = c ? nk[2 * k] : nk[2 * k + 1];
    }
#pragma unroll
    for (int k = 0; k < 2; ++k) {
      bool c = nb[2 * k] >= nb[2 * k + 1];
      nb[k] = c ? nb[2 * k] : nb[2 * k + 1];
      nk[k] = c ? nk[2 * k] : nk[2 * k + 1];
    }
    bool c0w = nb[0] >= nb[1];
    unsigned tb = c0w ? nb[0] : nb[1];
    unsigned tk = c0w ? nk[0] : nk[1];
    unsigned tag = (unsigned)tagbase - (tk << 8);  // == 4095 - (tk*256 + tid)
    // ---- single-phase wave reduce on combined key (bits<<12 | tag) ----
    u64 key = ((u64)tb << 12) | (u64)tag;
    u64 wk = wave_maxu64(key);
    if (lane == 63) s_pd[j & 1][wave] = wk;
    __syncthreads();
    // ---- uniform cross-wave scan: u64 max of 4 keys ----
    u64 k0 = s_pd[j & 1][0], k1 = s_pd[j & 1][1];
    u64 k2 = s_pd[j & 1][2], k3 = s_pd[j & 1][3];
    u64 ka = k0 > k1 ? k0 : k1;
    u64 kb2 = k2 > k3 ? k2 : k3;
    u64 bk = ka > kb2 ? ka : kb2;
    int fi = 4095 - (int)((unsigned)bk & 0xFFFu);
    float4 cw = s_xyzw[fi];  // uniform-address LDS broadcast
    cx = cw.x; cy = cw.y; cz = cw.z;
    if (tid == 0) s_fidx[j] = fi;
  }
  __syncthreads();
  for (int t = tid; t < SS; t += 256) {
    int idx = s_fidx[t];
    fps_idx[b * SS + t] = idx;
    float4 p = s_xyzw[idx];
    out_xyz[((size_t)b * SS + t) * 3 + 0] = p.x;
    out_xyz[((size_t)b * SS + t) * 3 + 1] = p.y;
    out_xyz[((size_t)b * SS + t) * 3 + 2] = p.z;
  }
}

// ---------------- kNN v4: radix tau + u64-key rank scan + fused mean/var ----------------
// Explicit barriers at the three ci/ck LDS RAW joints (safety; negligible cost).
__global__ __launch_bounds__(256) void knn_kernel(const float* __restrict__ xyzT,
                                                  const int* __restrict__ fps_idx,
                                                  int* __restrict__ knn_idx,
                                                  const float* __restrict__ points,
                                                  float* __restrict__ mean_out,
                                                  float* __restrict__ var_bins) {
  int wave = threadIdx.x >> 6, lane = threadIdx.x & 63;
  int q = blockIdx.x * 4 + wave, b = q >> 10;
  const float* bx = xyzT + (size_t)b * 3 * NN;
  const float* by = bx + NN;
  const float* bz = bx + 2 * NN;
  int qi = fps_idx[q];
  float qx = bx[qi], qy = by[qi], qz = bz[qi];
  float d[64];
  float lmin = 1e30f;
#pragma unroll
  for (int j = 0; j < 64; ++j) {
    int n = j * 64 + lane;
    float dx = bx[n] - qx, dy = by[n] - qy, dz = bz[n] - qz;
    d[j] = fmaf(dx, dx, fmaf(dy, dy, dz * dz));
    lmin = fminf(lmin, d[j]);
  }
  unsigned lb = __float_as_uint(lmin);
  unsigned res = 0;
#pragma unroll
  for (int bit = 30; bit >= 0; --bit) {
    unsigned t = res | (1u << bit);
    int c = __popcll(__ballot(lb < t));
    res = (c < 32) ? t : res;
  }
  float tau = __uint_as_float(res) * 1.00001f + 1e-20f;  // margin covers f32 dist err

  __shared__ int ci[4][512];
  __shared__ u64 ck[4][512];
  int cnt = 0;
#pragma unroll
  for (int j = 0; j < 64; ++j) {
    bool pred = (d[j] <= tau);
    unsigned long long mask = __ballot(pred);
    if (pred) {
      int pos = cnt + __popcll(mask & ((1ull << lane) - 1ull));
      if (pos < 512) ci[wave][pos] = j * 64 + lane;
    }
    cnt += __popcll(mask);
  }
  if (cnt > 512) cnt = 512;
  __syncthreads();  // ci compaction-writes -> ci reads below
  double qx64 = (double)qx, qy64 = (double)qy, qz64 = (double)qz;
  for (int p = lane; p < cnt; p += 64) {
    int n = ci[wave][p];
    double dx = (double)bx[n] - qx64;
    double dy = (double)by[n] - qy64;
    double dz = (double)bz[n] - qz64;
    double d64 = fma(dx, dx, fma(dy, dy, dz * dz));
    ck[wave][p] = ((u64)__double_as_longlong(d64) & ~0xFFFull) | (u64)n;
  }
  __syncthreads();  // ck writes -> ck rank-scan reads
  for (int p = lane; p < cnt; p += 64) {
    u64 mykey = ck[wave][p];
    int rank = 0;
    int r = 0;
    for (; r + 4 <= cnt; r += 4) {
      u64 k0 = ck[wave][r + 0], k1 = ck[wave][r + 1];
      u64 k2 = ck[wave][r + 2], k3 = ck[wave][r + 3];
      rank += (k0 < mykey) + (k1 < mykey) + (k2 < mykey) + (k3 < mykey);
    }
    for (; r < cnt; ++r) rank += (ck[wave][r] < mykey) ? 1 : 0;
    if (rank < KK) {
      int n = (int)(mykey & 0xFFFull);
      knn_idx[(size_t)q * KK + rank] = n;
      ci[wave][rank] = n;  // park for fused mean/var
    }
  }
  __syncthreads();  // ci rank-writes -> ci reads in mean/var
  // ---- fused mean over K + per-batch sum of diff^2 (lane = channel) ----
  const float* pb = points + (size_t)b * NN * CH;
  float s1 = 0.f, s2 = 0.f;
#pragma unroll
  for (int k = 0; k < KK; ++k) {
    float x = pb[(size_t)ci[wave][k] * CH + lane];
    s1 += x;
    s2 = fmaf(x, x, s2);
  }
  float m = s1 * (1.0f / 32.0f);
  mean_out[(size_t)q * CH + lane] = m;
  float part = s2 - s1 * m;
#pragma unroll
  for (int mm = 1; mm < 64; mm <<= 1) part += __shfl_xor(part, mm, 64);
  if (lane == 0) atomicAdd(&var_bins[b * 64 + (q & 63)], part);
}

__global__ void fin_std_kernel(const float* __restrict__ bins, float* __restrict__ rstd) {
  int t = threadIdx.x;
  if (t < BB) {
    float s = 0.f;
    for (int i = 0; i < 64; ++i) s += bins[t * 64 + i];
    float var = s / (float)(SS * KK * CH - 1);
    rstd[t] = 1.0f / (sqrtf(var) + 1e-5f);
  }
}

__global__ void fin_bn_kernel(const float* __restrict__ bins, const float* __restrict__ g,
                              const float* __restrict__ be, float* __restrict__ coef) {
  int o = threadIdx.x;  // < 128
  float s = 0.f, qq = 0.f;
  for (int bin = 0; bin < 64; ++bin) {
    s += bins[(bin * 128 + o) * 2 + 0];
    qq += bins[(bin * 128 + o) * 2 + 1];
  }
  constexpr float invM = 1.0f / (float)(BB * SS * KK);
  float mean = s * invM;
  float var = qq * invM - mean * mean;
  if (var < 0.f) var = 0.f;
  float sc = g[o] / sqrtf(var + 1e-5f);
  coef[2 * o] = sc;
  coef[2 * o + 1] = be[o] - mean * sc;
}

// ---------------- GEMM passes ----------------
// PASS 0: X->h1, BN1 stats.  PASS 1: X->h1->P->h2, BN2 stats.
// PASS 2: X->h1->P->h2, BN2 + residual + lrelu + maxpool -> out.
// XCD-partitioned; software-pipelined gather; packed bf16 cvt; BN stats in
// registers across all chunks, one merge per block.
template <int PASS>
__global__ __launch_bounds__(256, 2) void gemm_pass(
    const float* __restrict__ points, const int* __restrict__ kidx, const int* __restrict__ fidx,
    const float* __restrict__ mean, const float* __restrict__ rstd,
    const float* __restrict__ alpha, const float* __restrict__ beta,
    const short* __restrict__ w1bf, const short* __restrict__ w2bf,
    const float* __restrict__ coef1, const float* __restrict__ coef2,
    float* __restrict__ bins_out, float* __restrict__ out_pooled) {
  __shared__ short Xs[GPC * 32 * LDW];
  __shared__ short Ps[(PASS >= 1) ? (GPC * 32 * LDW) : 8];
  __shared__ float sMean[2][GPC][64];
  __shared__ float sAlpha[64], sBeta[64];
  __shared__ float sCoef1[256], sCoef2[256];
  __shared__ float bnS[128], bnQ[128];

  int tid = threadIdx.x;
  int wave = tid >> 6, lane = tid & 63;
  int q4 = lane >> 4, l15 = lane & 15;
  int ohalf = wave & 1, gsel = wave >> 1;

  // W fragments -> registers
  v8s wf1[4][4];
  v8s wf2[4][4];
#pragma unroll
  for (int ot = 0; ot < 4; ++ot) {
    int row = ohalf * 64 + ot * 16 + l15;
#pragma unroll
    for (int cs = 0; cs < 4; ++cs) {
      wf1[ot][cs] = *(const v8s*)(w1bf + row * 128 + cs * 32 + q4 * 8);
      if constexpr (PASS >= 1) wf2[ot][cs] = *(const v8s*)(w2bf + row * 128 + cs * 32 + q4 * 8);
    }
  }
  if (tid < 64) { sAlpha[tid] = alpha[tid]; sBeta[tid] = beta[tid]; }
  if constexpr (PASS >= 1) sCoef1[tid] = coef1[tid];
  if constexpr (PASS == 2) sCoef2[tid] = coef2[tid];
  if constexpr (PASS <= 1) {
    if (tid < 128) { bnS[tid] = 0.f; bnQ[tid] = 0.f; }
  }

  int xcd = blockIdx.x & 7, slot = blockIdx.x >> 3;  // slot 0..63
  int sg = tid >> 7, sk = (tid >> 2) & 31, qr = tid & 3;
  int ch0 = (qr & 1) * 32;
  bool norm = (qr < 2);
  float rsA = rstd[xcd], rsB = rstd[xcd + 8];

  float svA[4][4] = {}, sqA[4][4] = {};  // register BN-stat accumulators (PASS<=1)

  // ---- pipeline preamble: chunk(slot) points->regs, mean->sMean[0] ----
  float4 ldv[8];
  {
    int t = slot;
    int batch = xcd + ((t >> 9) << 3);
    int g0 = batch * SS + (t & 511) * GPC;
    int ggl = g0 + sg;
    int row = norm ? kidx[(size_t)ggl * KK + sk] : fidx[ggl];
    const float* src = points + (size_t)batch * NN * CH + (size_t)row * CH + ch0;
#pragma unroll
    for (int u = 0; u < 8; ++u) ldv[u] = *(const float4*)(src + u * 4);
    if (tid < 32) {
      int sg2 = tid >> 4, off = (tid & 15) << 2;
      float4 mv = *(const float4*)(mean + (size_t)(g0 + sg2) * CH + off);
      *(float4*)&sMean[0][sg2][off] = mv;
    }
  }
  __syncthreads();

  for (int it = 0; it < 16; ++it) {
    int t = slot + it * 64;
    int batch = xcd + ((t >> 9) << 3);
    int g0 = batch * SS + (t & 511) * GPC;
    int tn = (it < 15) ? t + 64 : t;
    int batch_n = xcd + ((tn >> 9) << 3);
    int g0_n = batch_n * SS + (tn & 511) * GPC;
    int ggl_n = g0_n + sg;
    int row_n = norm ? kidx[(size_t)ggl_n * KK + sk] : fidx[ggl_n];

    // ---- stage chunk t: prefetched regs + sMean tile -> Xs ----
    {
      float rs = (t >> 9) ? rsB : rsA;
      unsigned pks[16];
#pragma unroll
      for (int u = 0; u < 8; ++u) {
        float4 vv = ldv[u];
        if (norm) {
          float4 mv = *(const float4*)&sMean[it & 1][sg][ch0 + u * 4];
          float4 av = *(const float4*)&sAlpha[ch0 + u * 4];
          float4 bv = *(const float4*)&sBeta[ch0 + u * 4];
          vv.x = fmaf((vv.x - mv.x) * rs, av.x, bv.x);
          vv.y = fmaf((vv.y - mv.y) * rs, av.y, bv.y);
          vv.z = fmaf((vv.z - mv.z) * rs, av.z, bv.z);
          vv.w = fmaf((vv.w - mv.w) * rs, av.w, bv.w);
        }
        pks[2 * u + 0] = pkbf(vv.x, vv.y);
        pks[2 * u + 1] = pkbf(vv.z, vv.w);
      }
      short* dst = &Xs[(sg * 32 + sk) * LDW + qr * 32];
#pragma unroll
      for (int p2 = 0; p2 < 4; ++p2) *(uint4*)(dst + p2 * 8) = ((uint4*)pks)[p2];
    }
    __syncthreads();

    // ---- GEMM1: h1 = W1 * X ----
    v4f acc[4][2] = {};
#pragma unroll
    for (int cs = 0; cs < 4; ++cs) {
      v8s bfr[2];
#pragma unroll
      for (int kt = 0; kt < 2; ++kt)
        bfr[kt] = *(const v8s*)&Xs[(gsel * 32 + kt * 16 + l15) * LDW + cs * 32 + q4 * 8];
#pragma unroll
      for (int ot = 0; ot < 4; ++ot)
#pragma unroll
        for (int kt = 0; kt < 2; ++kt)
          acc[ot][kt] = __builtin_amdgcn_mfma_f32_16x16x32_bf16(wf1[ot][cs], bfr[kt], acc[ot][kt], 0, 0, 0);
    }

    // ---- issue next-chunk gather (hidden behind GEMM2/stats) ----
    float4 mpre;
    {
      const float* src = points + (size_t)batch_n * NN * CH + (size_t)row_n * CH + ch0;
#pragma unroll
      for (int u = 0; u < 8; ++u) ldv[u] = *(const float4*)(src + u * 4);
      if (tid < 32) {
        int sg2 = tid >> 4, off = (tid & 15) << 2;
        mpre = *(const float4*)(mean + (size_t)(g0_n + sg2) * CH + off);
      }
    }

    if constexpr (PASS == 0) {
#pragma unroll
      for (int ot = 0; ot < 4; ++ot)
#pragma unroll
        for (int r = 0; r < 4; ++r) {
          float a0 = acc[ot][0][r], a1 = acc[ot][1][r];
          svA[ot][r] += a0 + a1;
          sqA[ot][r] = fmaf(a0, a0, fmaf(a1, a1, sqA[ot][r]));
        }
    } else {
      // ---- P = lrelu(bn1(h1)) -> Ps ----
#pragma unroll
      for (int ot = 0; ot < 4; ++ot) {
        int o0 = ohalf * 64 + ot * 16 + q4 * 4;
#pragma unroll
        for (int kt = 0; kt < 2; ++kt) {
          float hv[4];
#pragma unroll
          for (int r = 0; r < 4; ++r) {
            float h = fmaf(acc[ot][kt][r], sCoef1[2 * (o0 + r)], sCoef1[2 * (o0 + r) + 1]);
            hv[r] = (h >= 0.f) ? h : 0.01f * h;
          }
          *(uint2*)&Ps[(gsel * 32 + kt * 16 + l15) * LDW + o0] =
              make_uint2(pkbf(hv[0], hv[1]), pkbf(hv[2], hv[3]));
        }
      }
      __syncthreads();

      // ---- GEMM2: h2 = W2 * P ----
      v4f acc2[4][2] = {};
#pragma unroll
      for (int cs = 0; cs < 4; ++cs) {
        v8s pfr[2];
#pragma unroll
        for (int kt = 0; kt < 2; ++kt)
          pfr[kt] = *(const v8s*)&Ps[(gsel * 32 + kt * 16 + l15) * LDW + cs * 32 + q4 * 8];
#pragma unroll
        for (int ot = 0; ot < 4; ++ot)
#pragma unroll
          for (int kt = 0; kt < 2; ++kt)
            acc2[ot][kt] = __builtin_amdgcn_mfma_f32_16x16x32_bf16(wf2[ot][cs], pfr[kt], acc2[ot][kt], 0, 0, 0);
      }

      if constexpr (PASS == 1) {
#pragma unroll
        for (int ot = 0; ot < 4; ++ot)
#pragma unroll
          for (int r = 0; r < 4; ++r) {
            float a0 = acc2[ot][0][r], a1 = acc2[ot][1][r];
            svA[ot][r] += a0 + a1;
            sqA[ot][r] = fmaf(a0, a0, fmaf(a1, a1, sqA[ot][r]));
          }
      } else {
        // ---- epilogue: lrelu(bn2(h2) + X) , max over k (DPP), store ----
#pragma unroll
        for (int ot = 0; ot < 4; ++ot) {
          int o0 = ohalf * 64 + ot * 16 + q4 * 4;
          float mx[4] = {-1e30f, -1e30f, -1e30f, -1e30f};
#pragma unroll
          for (int kt = 0; kt < 2; ++kt) {
            v4s xv = *(const v4s*)&Xs[(gsel * 32 + kt * 16 + l15) * LDW + o0];
#pragma unroll
            for (int r = 0; r < 4; ++r) {
              float h = fmaf(acc2[ot][kt][r], sCoef2[2 * (o0 + r)], sCoef2[2 * (o0 + r) + 1]);
              float val = h + bf2f(xv[r]);
              val = (val >= 0.f) ? val : 0.01f * val;
              mx[r] = fmaxf(mx[r], val);
            }
          }
#pragma unroll
          for (int r = 0; r < 4; ++r) mx[r] = max16(mx[r]);
          if (l15 == 0) {
            float4 o4;
            o4.x = mx[0]; o4.y = mx[1]; o4.z = mx[2]; o4.w = mx[3];
            *(float4*)(out_pooled + (size_t)(g0 + gsel) * DD + o0) = o4;
          }
        }
      }
    }
    if (tid < 32) *(float4*)&sMean[(it + 1) & 1][tid >> 4][(tid & 15) << 2] = mpre;
    __syncthreads();
  }

  if constexpr (PASS <= 1) {
#pragma unroll
    for (int ot = 0; ot < 4; ++ot)
#pragma unroll
      for (int r = 0; r < 4; ++r) {
        float sv = sum16(svA[ot][r]);
        float sq = sum16(sqA[ot][r]);
        if (l15 == 0) {
          int o0 = ohalf * 64 + ot * 16 + q4 * 4;
          atomicAdd(&bnS[o0 + r], sv);
          atomicAdd(&bnQ[o0 + r], sq);
        }
      }
    __syncthreads();
    if (tid < 128) {
      float* bb = bins_out + (((blockIdx.x & 63) * 128 + tid) << 1);
      atomicAdd(bb, bnS[tid]);
      atomicAdd(bb + 1, bnQ[tid]);
    }
  }
}

extern "C" void kernel_launch(void* const* d_in, const int* in_sizes, int n_in,
                              void* d_out, int out_size, void* d_ws, size_t ws_size,
                              hipStream_t stream) {
  const float* xyz    = (const float*)d_in[0];
  const float* points = (const float*)d_in[1];
  const float* alpha  = (const float*)d_in[2];
  const float* beta   = (const float*)d_in[3];
  const float* w1     = (const float*)d_in[4];
  const float* g1     = (const float*)d_in[6];
  const float* be1    = (const float*)d_in[7];
  const float* w2     = (const float*)d_in[8];
  const float* g2     = (const float*)d_in[10];
  const float* be2    = (const float*)d_in[11];
  float* out = (float*)d_out;

  char* w = (char*)d_ws;
  int* fps_i   = (int*)(w + OFF_FPSIDX);
  int* knn_i   = (int*)(w + OFF_KNN);
  float* meanp = (float*)(w + OFF_MEAN);
  float* varb  = (float*)(w + OFF_VARB);
  float* bins1 = (float*)(w + OFF_BINS1);
  float* bins2 = (float*)(w + OFF_BINS2);
  float* rstdp = (float*)(w + OFF_RSTD);
  float* coef1 = (float*)(w + OFF_COEF1);
  float* coef2 = (float*)(w + OFF_COEF2);
  short* w1b   = (short*)(w + OFF_W1BF);
  short* w2b   = (short*)(w + OFF_W2BF);
  float* xyzT  = (float*)(w + OFF_XYZT);

  hipMemsetAsync(w + MEMSET_OFF, 0, MEMSET_LEN, stream);
  prep_kernel<<<320, 256, 0, stream>>>(xyz, xyzT, w1, w2, w1b, w2b);
  fps_kernel<<<BB, 256, 0, stream>>>(xyzT, fps_i, out);
  knn_kernel<<<(BB * SS) / 4, 256, 0, stream>>>(xyzT, fps_i, knn_i, points, meanp, varb);
  fin_std_kernel<<<1, 64, 0, stream>>>(varb, rstdp);
  gemm_pass<0><<<GGRID, 256, 0, stream>>>(points, knn_i, fps_i, meanp, rstdp, alpha, beta,
                                          w1b, w2b, coef1, coef2, bins1, nullptr);
  fin_bn_kernel<<<1, 128, 0, stream>>>(bins1, g1, be1, coef1);
  gemm_pass<1><<<GGRID, 256, 0, stream>>>(points, knn_i, fps_i, meanp, rstdp, alpha, beta,
                                          w1b, w2b, coef1, coef2, bins2, nullptr);
  fin_bn_kernel<<<1, 128, 0, stream>>>(bins2, g2, be2, coef2);
  gemm_pass<2><<<GGRID, 256, 0, stream>>>(points, knn_i, fps_i, meanp, rstdp, alpha, beta,
                                          w1b, w2b, coef1, coef2, nullptr, out + (size_t)BB * SS * 3);
}

// Round 6
// 968.399 us; speedup vs baseline: 1.2087x; 1.2087x over previous
//
#include <hip/hip_runtime.h>

#define DI __device__ __forceinline__

typedef __attribute__((ext_vector_type(8))) short v8s;
typedef __attribute__((ext_vector_type(4))) short v4s;
typedef __attribute__((ext_vector_type(4))) float v4f;
typedef unsigned long long u64;

constexpr int BB = 16, NN = 4096, CH = 64, SS = 1024, KK = 32, DD = 128;
constexpr int LDW = 136;                 // LDS row stride in shorts (pad: 16B-aligned rows, <=2-way banks)
constexpr int GPC = 2;                   // groups per chunk in gemm passes
constexpr int GGRID = 512;

// ---- ws layout (bytes) ----
constexpr size_t OFF_FPSIDX = 0;         // int[16384]
constexpr size_t OFF_KNN    = 65536;     // int[524288]
constexpr size_t OFF_MEAN   = 2162688;   // float[1048576]
constexpr size_t OFF_VARB   = 6356992;   // float[1024]
constexpr size_t OFF_BINS1  = 6361088;   // float[16384]  [64][128][2]
constexpr size_t OFF_BINS2  = 6426624;   // float[16384]
constexpr size_t OFF_RSTD   = 6492160;   // float[16]
constexpr size_t OFF_COEF1  = 6492224;   // float[256]
constexpr size_t OFF_COEF2  = 6493248;   // float[256]
constexpr size_t OFF_W1BF   = 6494272;   // short[16384]
constexpr size_t OFF_W2BF   = 6527040;   // short[16384]
constexpr size_t OFF_XYZT   = 6559808;   // float[196608]  [B][3][N]
constexpr size_t MEMSET_OFF = OFF_VARB;
constexpr size_t MEMSET_LEN = 4096 + 65536 + 65536;

DI short f2bf(float f) {
  unsigned u = __float_as_uint(f);
  u = (u + 0x7fffu + ((u >> 16) & 1u)) >> 16;
  return (short)u;
}
DI float bf2f(short s) { return __uint_as_float(((unsigned)(unsigned short)s) << 16); }

// packed 2x f32 -> 2x bf16 (RNE); HW packed cvt if available
DI unsigned pkbf(float a, float b) {
#if __has_builtin(__builtin_amdgcn_cvt_pk_bf16_f32)
  typedef __attribute__((ext_vector_type(2))) __bf16 bf2_t;
  bf2_t r = __builtin_amdgcn_cvt_pk_bf16_f32(a, b);
  return *(unsigned*)&r;
#else
  return (unsigned)(unsigned short)f2bf(a) | ((unsigned)(unsigned short)f2bf(b) << 16);
#endif
}

// ---------------- prep: xyz transpose + weight cvt (merged launch) ----------------
__global__ void prep_kernel(const float* __restrict__ xyz, float* __restrict__ xyzT,
                            const float* __restrict__ w1, const float* __restrict__ w2,
                            short* __restrict__ w1b, short* __restrict__ w2b) {
  int bid = blockIdx.x;
  if (bid < 256) {
    int i = bid * 256 + threadIdx.x;  // < B*N
    int b = i >> 12, n = i & 4095;
    const float* s = xyz + (size_t)i * 3;
    float* d = xyzT + (size_t)b * 3 * NN + n;
    d[0] = s[0]; d[NN] = s[1]; d[2 * NN] = s[2];
  } else {
    int i = (bid - 256) * 256 + threadIdx.x;  // < 16384
    w1b[i] = f2bf(w1[i]);
    w2b[i] = f2bf(w2[i]);
  }
}

// tag low 12 bits of a double (monotone quantization per fixed tag)
DI double tag12(double d, int tag) {
  u64 b = (u64)__double_as_longlong(d);
  b = (b & ~0xFFFull) | (u64)(unsigned)tag;
  return __longlong_as_double((long long)b);
}
// 64-bit DPP fmax within a row of 16 lanes
template <int CTRL>
DI double dpp_fmax64(double x) {
  u64 b = (u64)__double_as_longlong(x);
  int lo = __builtin_amdgcn_update_dpp(0, (int)(unsigned)b, CTRL, 0xf, 0xf, true);
  int hi = __builtin_amdgcn_update_dpp(0, (int)(unsigned)(b >> 32), CTRL, 0xf, 0xf, true);
  double o = __longlong_as_double((long long)(((u64)(unsigned)hi << 32) | (unsigned)lo));
  return fmax(x, o);
}
DI double readlane_f64(double x, int l) {
  u64 b = (u64)__double_as_longlong(x);
  unsigned lo = (unsigned)__builtin_amdgcn_readlane((int)(unsigned)b, l);
  unsigned hi = (unsigned)__builtin_amdgcn_readlane((int)(unsigned)(b >> 32), l);
  return __longlong_as_double((long long)(((u64)hi << 32) | lo));
}

// DPP row rotate (within 16-lane row) for f32 reductions -- no LDS traffic.
template <int N>
DI float dpp_ror_f(float v) {
  return __int_as_float(__builtin_amdgcn_update_dpp(0, __float_as_int(v), 0x120 + N, 0xf, 0xf, true));
}
DI float sum16(float v) {
  v += dpp_ror_f<1>(v);
  v += dpp_ror_f<2>(v);
  v += dpp_ror_f<4>(v);
  v += dpp_ror_f<8>(v);
  return v;
}
DI float max16(float v) {
  v = fmaxf(v, dpp_ror_f<1>(v));
  v = fmaxf(v, dpp_ror_f<2>(v));
  v = fmaxf(v, dpp_ror_f<4>(v));
  v = fmaxf(v, dpp_ror_f<8>(v));
  return v;
}

// ---------------- FPS v7 (REVERTED): 256 threads (4 waves, 1/SIMD), 16 pts/lane ----------------
// Measured session-best: 567 us. Ledger of attempted replacements:
//   v8/v9 (asm reg pins):      572 us  (state lives in AGPRs; pins can't force it)
//   v10 (f32 inner + f64 tail): 628 us (per-round key rebuild: 16 cvt + tags + fmax tree)
//   v11 (two-phase u32 tail):   654 us (longer serial critical path)
//   v12 (u64 cndmask tail):     767 us (u64 max = cmp+2cndmask = 3 instr vs 1 v_max_f64)
// v7 wins because tags ride INSIDE m64 (tag cost amortized into the fmin) and
// f64 min/max are single instructions. Round is latency+issue bound at 1 wave/SIMD;
// tagged-f64 keys give fmax-reduce bit-identical to u64-key argmax with
// min-index tie-break. Do not restructure the tail again without new evidence.
__global__ __launch_bounds__(256, 1) void fps_kernel(const float* __restrict__ xyzT,
                                                     int* __restrict__ fps_idx,
                                                     float* __restrict__ out_xyz) {
  int b = blockIdx.x, tid = threadIdx.x;
  int wave = tid >> 6, lane = tid & 63;
  const float* bx = xyzT + (size_t)b * 3 * NN;
  const float* by = bx + NN;
  const float* bz = bx + 2 * NN;
  __shared__ float4 s_xyzw[NN];   // 64 KB coords broadcast
  __shared__ int s_fidx[SS];      // 4 KB selected indices
  __shared__ double s_pd[2][4];   // wave partial keys (dbuf by round parity)

  double px64[16], py64[16], pz64[16], pp64[16], m64[16];
  int tagbase = 4095 - tid;  // tag for point k: tagbase - k*256 == 4095 - gi
#pragma unroll
  for (int k = 0; k < 16; ++k) {
    int gi = k * 256 + tid;
    float x = bx[gi], y = by[gi], z = bz[gi];
    s_xyzw[gi] = make_float4(x, y, z, 0.f);
    px64[k] = (double)x; py64[k] = (double)y; pz64[k] = (double)z;
    pp64[k] = fma(px64[k], px64[k], fma(py64[k], py64[k], pz64[k] * pz64[k]));
    m64[k] = tag12(1e10, tagbase - k * 256);
  }
  if (tid == 0) s_fidx[0] = 0;
  __syncthreads();
  float4 c0 = s_xyzw[0];
  double cx = (double)c0.x, cy = (double)c0.y, cz = (double)c0.z;

  for (int j = 1; j < SS; ++j) {
    double cx2 = -2.0 * cx, cy2 = -2.0 * cy, cz2 = -2.0 * cz;
    double cc = fma(cx, cx, fma(cy, cy, cz * cz));
    double best;
#pragma unroll
    for (int k = 0; k < 16; ++k) {
      double d = fma(px64[k], cx2, fma(py64[k], cy2, fma(pz64[k], cz2, pp64[k] + cc)));
      d = tag12(d, tagbase - k * 256);
      m64[k] = fmin(m64[k], d);
      best = (k == 0) ? m64[0] : fmax(best, m64[k]);
    }
    // wave max: 4 DPP stages within row-of-16, then cross-row via readlane
    best = dpp_fmax64<0xB1>(best);   // quad_perm [1,0,3,2] : xor 1
    best = dpp_fmax64<0x4E>(best);   // quad_perm [2,3,0,1] : xor 2
    best = dpp_fmax64<0x141>(best);  // ROW_HALF_MIRROR     : xor 7
    best = dpp_fmax64<0x140>(best);  // ROW_MIRROR          : xor 15
    double r0 = readlane_f64(best, 0);
    double r1 = readlane_f64(best, 16);
    double r2 = readlane_f64(best, 32);
    double r3 = readlane_f64(best, 48);
    double bw = fmax(fmax(r0, r1), fmax(r2, r3));
    if (lane == 0) s_pd[j & 1][wave] = bw;
    __syncthreads();
    // cross-wave: uniform fmax scan of 4 partials
    double bk = fmax(fmax(s_pd[j & 1][0], s_pd[j & 1][1]),
                     fmax(s_pd[j & 1][2], s_pd[j & 1][3]));
    int fi = 4095 - (int)((u64)__double_as_longlong(bk) & 0xFFFull);
    float4 cw = s_xyzw[fi];  // uniform-address LDS broadcast
    cx = (double)cw.x; cy = (double)cw.y; cz = (double)cw.z;
    if (tid == 0) s_fidx[j] = fi;
  }
  __syncthreads();
  for (int t = tid; t < SS; t += 256) {
    int idx = s_fidx[t];
    fps_idx[b * SS + t] = idx;
    float4 p = s_xyzw[idx];
    out_xyz[((size_t)b * SS + t) * 3 + 0] = p.x;
    out_xyz[((size_t)b * SS + t) * 3 + 1] = p.y;
    out_xyz[((size_t)b * SS + t) * 3 + 2] = p.z;
  }
}

// ---------------- kNN v4: radix tau + u64-key rank scan + fused mean/var ----------------
// Explicit barriers at the three ci/ck LDS RAW joints (safety; negligible cost).
__global__ __launch_bounds__(256) void knn_kernel(const float* __restrict__ xyzT,
                                                  const int* __restrict__ fps_idx,
                                                  int* __restrict__ knn_idx,
                                                  const float* __restrict__ points,
                                                  float* __restrict__ mean_out,
                                                  float* __restrict__ var_bins) {
  int wave = threadIdx.x >> 6, lane = threadIdx.x & 63;
  int q = blockIdx.x * 4 + wave, b = q >> 10;
  const float* bx = xyzT + (size_t)b * 3 * NN;
  const float* by = bx + NN;
  const float* bz = bx + 2 * NN;
  int qi = fps_idx[q];
  float qx = bx[qi], qy = by[qi], qz = bz[qi];
  float d[64];
  float lmin = 1e30f;
#pragma unroll
  for (int j = 0; j < 64; ++j) {
    int n = j * 64 + lane;
    float dx = bx[n] - qx, dy = by[n] - qy, dz = bz[n] - qz;
    d[j] = fmaf(dx, dx, fmaf(dy, dy, dz * dz));
    lmin = fminf(lmin, d[j]);
  }
  unsigned lb = __float_as_uint(lmin);
  unsigned res = 0;
#pragma unroll
  for (int bit = 30; bit >= 0; --bit) {
    unsigned t = res | (1u << bit);
    int c = __popcll(__ballot(lb < t));
    res = (c < 32) ? t : res;
  }
  float tau = __uint_as_float(res) * 1.00001f + 1e-20f;  // margin covers f32 dist err

  __shared__ int ci[4][512];
  __shared__ u64 ck[4][512];
  int cnt = 0;
#pragma unroll
  for (int j = 0; j < 64; ++j) {
    bool pred = (d[j] <= tau);
    unsigned long long mask = __ballot(pred);
    if (pred) {
      int pos = cnt + __popcll(mask & ((1ull << lane) - 1ull));
      if (pos < 512) ci[wave][pos] = j * 64 + lane;
    }
    cnt += __popcll(mask);
  }
  if (cnt > 512) cnt = 512;
  __syncthreads();  // ci compaction-writes -> ci reads below
  double qx64 = (double)qx, qy64 = (double)qy, qz64 = (double)qz;
  for (int p = lane; p < cnt; p += 64) {
    int n = ci[wave][p];
    double dx = (double)bx[n] - qx64;
    double dy = (double)by[n] - qy64;
    double dz = (double)bz[n] - qz64;
    double d64 = fma(dx, dx, fma(dy, dy, dz * dz));
    ck[wave][p] = ((u64)__double_as_longlong(d64) & ~0xFFFull) | (u64)n;
  }
  __syncthreads();  // ck writes -> ck rank-scan reads
  for (int p = lane; p < cnt; p += 64) {
    u64 mykey = ck[wave][p];
    int rank = 0;
    int r = 0;
    for (; r + 4 <= cnt; r += 4) {
      u64 k0 = ck[wave][r + 0], k1 = ck[wave][r + 1];
      u64 k2 = ck[wave][r + 2], k3 = ck[wave][r + 3];
      rank += (k0 < mykey) + (k1 < mykey) + (k2 < mykey) + (k3 < mykey);
    }
    for (; r < cnt; ++r) rank += (ck[wave][r] < mykey) ? 1 : 0;
    if (rank < KK) {
      int n = (int)(mykey & 0xFFFull);
      knn_idx[(size_t)q * KK + rank] = n;
      ci[wave][rank] = n;  // park for fused mean/var
    }
  }
  __syncthreads();  // ci rank-writes -> ci reads in mean/var
  // ---- fused mean over K + per-batch sum of diff^2 (lane = channel) ----
  const float* pb = points + (size_t)b * NN * CH;
  float s1 = 0.f, s2 = 0.f;
#pragma unroll
  for (int k = 0; k < KK; ++k) {
    float x = pb[(size_t)ci[wave][k] * CH + lane];
    s1 += x;
    s2 = fmaf(x, x, s2);
  }
  float m = s1 * (1.0f / 32.0f);
  mean_out[(size_t)q * CH + lane] = m;
  float part = s2 - s1 * m;
#pragma unroll
  for (int mm = 1; mm < 64; mm <<= 1) part += __shfl_xor(part, mm, 64);
  if (lane == 0) atomicAdd(&var_bins[b * 64 + (q & 63)], part);
}

__global__ void fin_std_kernel(const float* __restrict__ bins, float* __restrict__ rstd) {
  int t = threadIdx.x;
  if (t < BB) {
    float s = 0.f;
    for (int i = 0; i < 64; ++i) s += bins[t * 64 + i];
    float var = s / (float)(SS * KK * CH - 1);
    rstd[t] = 1.0f / (sqrtf(var) + 1e-5f);
  }
}

__global__ void fin_bn_kernel(const float* __restrict__ bins, const float* __restrict__ g,
                              const float* __restrict__ be, float* __restrict__ coef) {
  int o = threadIdx.x;  // < 128
  float s = 0.f, qq = 0.f;
  for (int bin = 0; bin < 64; ++bin) {
    s += bins[(bin * 128 + o) * 2 + 0];
    qq += bins[(bin * 128 + o) * 2 + 1];
  }
  constexpr float invM = 1.0f / (float)(BB * SS * KK);
  float mean = s * invM;
  float var = qq * invM - mean * mean;
  if (var < 0.f) var = 0.f;
  float sc = g[o] / sqrtf(var + 1e-5f);
  coef[2 * o] = sc;
  coef[2 * o + 1] = be[o] - mean * sc;
}

// ---------------- GEMM passes ----------------
// PASS 0: X->h1, BN1 stats.  PASS 1: X->h1->P->h2, BN2 stats.
// PASS 2: X->h1->P->h2, BN2 + residual + lrelu + maxpool -> out.
// XCD-partitioned; software-pipelined gather; packed bf16 cvt; BN stats in
// registers across all chunks, one merge per block.
template <int PASS>
__global__ __launch_bounds__(256, 2) void gemm_pass(
    const float* __restrict__ points, const int* __restrict__ kidx, const int* __restrict__ fidx,
    const float* __restrict__ mean, const float* __restrict__ rstd,
    const float* __restrict__ alpha, const float* __restrict__ beta,
    const short* __restrict__ w1bf, const short* __restrict__ w2bf,
    const float* __restrict__ coef1, const float* __restrict__ coef2,
    float* __restrict__ bins_out, float* __restrict__ out_pooled) {
  __shared__ short Xs[GPC * 32 * LDW];
  __shared__ short Ps[(PASS >= 1) ? (GPC * 32 * LDW) : 8];
  __shared__ float sMean[2][GPC][64];
  __shared__ float sAlpha[64], sBeta[64];
  __shared__ float sCoef1[256], sCoef2[256];
  __shared__ float bnS[128], bnQ[128];

  int tid = threadIdx.x;
  int wave = tid >> 6, lane = tid & 63;
  int q4 = lane >> 4, l15 = lane & 15;
  int ohalf = wave & 1, gsel = wave >> 1;

  // W fragments -> registers
  v8s wf1[4][4];
  v8s wf2[4][4];
#pragma unroll
  for (int ot = 0; ot < 4; ++ot) {
    int row = ohalf * 64 + ot * 16 + l15;
#pragma unroll
    for (int cs = 0; cs < 4; ++cs) {
      wf1[ot][cs] = *(const v8s*)(w1bf + row * 128 + cs * 32 + q4 * 8);
      if constexpr (PASS >= 1) wf2[ot][cs] = *(const v8s*)(w2bf + row * 128 + cs * 32 + q4 * 8);
    }
  }
  if (tid < 64) { sAlpha[tid] = alpha[tid]; sBeta[tid] = beta[tid]; }
  if constexpr (PASS >= 1) sCoef1[tid] = coef1[tid];
  if constexpr (PASS == 2) sCoef2[tid] = coef2[tid];
  if constexpr (PASS <= 1) {
    if (tid < 128) { bnS[tid] = 0.f; bnQ[tid] = 0.f; }
  }

  int xcd = blockIdx.x & 7, slot = blockIdx.x >> 3;  // slot 0..63
  int sg = tid >> 7, sk = (tid >> 2) & 31, qr = tid & 3;
  int ch0 = (qr & 1) * 32;
  bool norm = (qr < 2);
  float rsA = rstd[xcd], rsB = rstd[xcd + 8];

  float svA[4][4] = {}, sqA[4][4] = {};  // register BN-stat accumulators (PASS<=1)

  // ---- pipeline preamble: chunk(slot) points->regs, mean->sMean[0] ----
  float4 ldv[8];
  {
    int t = slot;
    int batch = xcd + ((t >> 9) << 3);
    int g0 = batch * SS + (t & 511) * GPC;
    int ggl = g0 + sg;
    int row = norm ? kidx[(size_t)ggl * KK + sk] : fidx[ggl];
    const float* src = points + (size_t)batch * NN * CH + (size_t)row * CH + ch0;
#pragma unroll
    for (int u = 0; u < 8; ++u) ldv[u] = *(const float4*)(src + u * 4);
    if (tid < 32) {
      int sg2 = tid >> 4, off = (tid & 15) << 2;
      float4 mv = *(const float4*)(mean + (size_t)(g0 + sg2) * CH + off);
      *(float4*)&sMean[0][sg2][off] = mv;
    }
  }
  __syncthreads();

  for (int it = 0; it < 16; ++it) {
    int t = slot + it * 64;
    int batch = xcd + ((t >> 9) << 3);
    int g0 = batch * SS + (t & 511) * GPC;
    int tn = (it < 15) ? t + 64 : t;
    int batch_n = xcd + ((tn >> 9) << 3);
    int g0_n = batch_n * SS + (tn & 511) * GPC;
    int ggl_n = g0_n + sg;
    int row_n = norm ? kidx[(size_t)ggl_n * KK + sk] : fidx[ggl_n];

    // ---- stage chunk t: prefetched regs + sMean tile -> Xs ----
    {
      float rs = (t >> 9) ? rsB : rsA;
      unsigned pks[16];
#pragma unroll
      for (int u = 0; u < 8; ++u) {
        float4 vv = ldv[u];
        if (norm) {
          float4 mv = *(const float4*)&sMean[it & 1][sg][ch0 + u * 4];
          float4 av = *(const float4*)&sAlpha[ch0 + u * 4];
          float4 bv = *(const float4*)&sBeta[ch0 + u * 4];
          vv.x = fmaf((vv.x - mv.x) * rs, av.x, bv.x);
          vv.y = fmaf((vv.y - mv.y) * rs, av.y, bv.y);
          vv.z = fmaf((vv.z - mv.z) * rs, av.z, bv.z);
          vv.w = fmaf((vv.w - mv.w) * rs, av.w, bv.w);
        }
        pks[2 * u + 0] = pkbf(vv.x, vv.y);
        pks[2 * u + 1] = pkbf(vv.z, vv.w);
      }
      short* dst = &Xs[(sg * 32 + sk) * LDW + qr * 32];
#pragma unroll
      for (int p2 = 0; p2 < 4; ++p2) *(uint4*)(dst + p2 * 8) = ((uint4*)pks)[p2];
    }
    __syncthreads();

    // ---- GEMM1: h1 = W1 * X ----
    v4f acc[4][2] = {};
#pragma unroll
    for (int cs = 0; cs < 4; ++cs) {
      v8s bfr[2];
#pragma unroll
      for (int kt = 0; kt < 2; ++kt)
        bfr[kt] = *(const v8s*)&Xs[(gsel * 32 + kt * 16 + l15) * LDW + cs * 32 + q4 * 8];
#pragma unroll
      for (int ot = 0; ot < 4; ++ot)
#pragma unroll
        for (int kt = 0; kt < 2; ++kt)
          acc[ot][kt] = __builtin_amdgcn_mfma_f32_16x16x32_bf16(wf1[ot][cs], bfr[kt], acc[ot][kt], 0, 0, 0);
    }

    // ---- issue next-chunk gather (hidden behind GEMM2/stats) ----
    float4 mpre;
    {
      const float* src = points + (size_t)batch_n * NN * CH + (size_t)row_n * CH + ch0;
#pragma unroll
      for (int u = 0; u < 8; ++u) ldv[u] = *(const float4*)(src + u * 4);
      if (tid < 32) {
        int sg2 = tid >> 4, off = (tid & 15) << 2;
        mpre = *(const float4*)(mean + (size_t)(g0_n + sg2) * CH + off);
      }
    }

    if constexpr (PASS == 0) {
#pragma unroll
      for (int ot = 0; ot < 4; ++ot)
#pragma unroll
        for (int r = 0; r < 4; ++r) {
          float a0 = acc[ot][0][r], a1 = acc[ot][1][r];
          svA[ot][r] += a0 + a1;
          sqA[ot][r] = fmaf(a0, a0, fmaf(a1, a1, sqA[ot][r]));
        }
    } else {
      // ---- P = lrelu(bn1(h1)) -> Ps ----
#pragma unroll
      for (int ot = 0; ot < 4; ++ot) {
        int o0 = ohalf * 64 + ot * 16 + q4 * 4;
#pragma unroll
        for (int kt = 0; kt < 2; ++kt) {
          float hv[4];
#pragma unroll
          for (int r = 0; r < 4; ++r) {
            float h = fmaf(acc[ot][kt][r], sCoef1[2 * (o0 + r)], sCoef1[2 * (o0 + r) + 1]);
            hv[r] = (h >= 0.f) ? h : 0.01f * h;
          }
          *(uint2*)&Ps[(gsel * 32 + kt * 16 + l15) * LDW + o0] =
              make_uint2(pkbf(hv[0], hv[1]), pkbf(hv[2], hv[3]));
        }
      }
      __syncthreads();

      // ---- GEMM2: h2 = W2 * P ----
      v4f acc2[4][2] = {};
#pragma unroll
      for (int cs = 0; cs < 4; ++cs) {
        v8s pfr[2];
#pragma unroll
        for (int kt = 0; kt < 2; ++kt)
          pfr[kt] = *(const v8s*)&Ps[(gsel * 32 + kt * 16 + l15) * LDW + cs * 32 + q4 * 8];
#pragma unroll
        for (int ot = 0; ot < 4; ++ot)
#pragma unroll
          for (int kt = 0; kt < 2; ++kt)
            acc2[ot][kt] = __builtin_amdgcn_mfma_f32_16x16x32_bf16(wf2[ot][cs], pfr[kt], acc2[ot][kt], 0, 0, 0);
      }

      if constexpr (PASS == 1) {
#pragma unroll
        for (int ot = 0; ot < 4; ++ot)
#pragma unroll
          for (int r = 0; r < 4; ++r) {
            float a0 = acc2[ot][0][r], a1 = acc2[ot][1][r];
            svA[ot][r] += a0 + a1;
            sqA[ot][r] = fmaf(a0, a0, fmaf(a1, a1, sqA[ot][r]));
          }
      } else {
        // ---- epilogue: lrelu(bn2(h2) + X) , max over k (DPP), store ----
#pragma unroll
        for (int ot = 0; ot < 4; ++ot) {
          int o0 = ohalf * 64 + ot * 16 + q4 * 4;
          float mx[4] = {-1e30f, -1e30f, -1e30f, -1e30f};
#pragma unroll
          for (int kt = 0; kt < 2; ++kt) {
            v4s xv = *(const v4s*)&Xs[(gsel * 32 + kt * 16 + l15) * LDW + o0];
#pragma unroll
            for (int r = 0; r < 4; ++r) {
              float h = fmaf(acc2[ot][kt][r], sCoef2[2 * (o0 + r)], sCoef2[2 * (o0 + r) + 1]);
              float val = h + bf2f(xv[r]);
              val = (val >= 0.f) ? val : 0.01f * val;
              mx[r] = fmaxf(mx[r], val);
            }
          }
#pragma unroll
          for (int r = 0; r < 4; ++r) mx[r] = max16(mx[r]);
          if (l15 == 0) {
            float4 o4;
            o4.x = mx[0]; o4.y = mx[1]; o4.z = mx[2]; o4.w = mx[3];
            *(float4*)(out_pooled + (size_t)(g0 + gsel) * DD + o0) = o4;
          }
        }
      }
    }
    if (tid < 32) *(float4*)&sMean[(it + 1) & 1][tid >> 4][(tid & 15) << 2] = mpre;
    __syncthreads();
  }

  if constexpr (PASS <= 1) {
#pragma unroll
    for (int ot = 0; ot < 4; ++ot)
#pragma unroll
      for (int r = 0; r < 4; ++r) {
        float sv = sum16(svA[ot][r]);
        float sq = sum16(sqA[ot][r]);
        if (l15 == 0) {
          int o0 = ohalf * 64 + ot * 16 + q4 * 4;
          atomicAdd(&bnS[o0 + r], sv);
          atomicAdd(&bnQ[o0 + r], sq);
        }
      }
    __syncthreads();
    if (tid < 128) {
      float* bb = bins_out + (((blockIdx.x & 63) * 128 + tid) << 1);
      atomicAdd(bb, bnS[tid]);
      atomicAdd(bb + 1, bnQ[tid]);
    }
  }
}

extern "C" void kernel_launch(void* const* d_in, const int* in_sizes, int n_in,
                              void* d_out, int out_size, void* d_ws, size_t ws_size,
                              hipStream_t stream) {
  const float* xyz    = (const float*)d_in[0];
  const float* points = (const float*)d_in[1];
  const float* alpha  = (const float*)d_in[2];
  const float* beta   = (const float*)d_in[3];
  const float* w1     = (const float*)d_in[4];
  const float* g1     = (const float*)d_in[6];
  const float* be1    = (const float*)d_in[7];
  const float* w2     = (const float*)d_in[8];
  const float* g2     = (const float*)d_in[10];
  const float* be2    = (const float*)d_in[11];
  float* out = (float*)d_out;

  char* w = (char*)d_ws;
  int* fps_i   = (int*)(w + OFF_FPSIDX);
  int* knn_i   = (int*)(w + OFF_KNN);
  float* meanp = (float*)(w + OFF_MEAN);
  float* varb  = (float*)(w + OFF_VARB);
  float* bins1 = (float*)(w + OFF_BINS1);
  float* bins2 = (float*)(w + OFF_BINS2);
  float* rstdp = (float*)(w + OFF_RSTD);
  float* coef1 = (float*)(w + OFF_COEF1);
  float* coef2 = (float*)(w + OFF_COEF2);
  short* w1b   = (short*)(w + OFF_W1BF);
  short* w2b   = (short*)(w + OFF_W2BF);
  float* xyzT  = (float*)(w + OFF_XYZT);

  hipMemsetAsync(w + MEMSET_OFF, 0, MEMSET_LEN, stream);
  prep_kernel<<<320, 256, 0, stream>>>(xyz, xyzT, w1, w2, w1b, w2b);
  fps_kernel<<<BB, 256, 0, stream>>>(xyzT, fps_i, out);
  knn_kernel<<<(BB * SS) / 4, 256, 0, stream>>>(xyzT, fps_i, knn_i, points, meanp, varb);
  fin_std_kernel<<<1, 64, 0, stream>>>(varb, rstdp);
  gemm_pass<0><<<GGRID, 256, 0, stream>>>(points, knn_i, fps_i, meanp, rstdp, alpha, beta,
                                          w1b, w2b, coef1, coef2, bins1, nullptr);
  fin_bn_kernel<<<1, 128, 0, stream>>>(bins1, g1, be1, coef1);
  gemm_pass<1><<<GGRID, 256, 0, stream>>>(points, knn_i, fps_i, meanp, rstdp, alpha, beta,
                                          w1b, w2b, coef1, coef2, bins2, nullptr);
  fin_bn_kernel<<<1, 128, 0, stream>>>(bins2, g2, be2, coef2);
  gemm_pass<2><<<GGRID, 256, 0, stream>>>(points, knn_i, fps_i, meanp, rstdp, alpha, beta,
                                          w1b, w2b, coef1, coef2, nullptr, out + (size_t)BB * SS * 3);
}